// Round 10
// baseline (543.664 us; speedup 1.0000x reference)
//
#include <hip/hip_runtime.h>
#include <hip/hip_cooperative_groups.h>

namespace cg = cooperative_groups;

#define NCH 64      // channels
#define KOFF 27     // kernel offsets
#define EPSV 1e-5f

typedef __attribute__((ext_vector_type(8))) short  bf16x8;
typedef __attribute__((ext_vector_type(4))) float  f32x4;
typedef __attribute__((ext_vector_type(8))) unsigned short u16x8;

__device__ __forceinline__ unsigned short f2bf(float x) {
    unsigned int u = __float_as_uint(x);
    u += 0x7fffu + ((u >> 16) & 1u);       // round-to-nearest-even
    return (unsigned short)(u >> 16);
}

struct MegaParams {
    const float* feats; const int* nbr;
    const float* W1; const float* b1; const float* g1; const float* be1;
    const float* W2; const float* b2; const float* g2; const float* be2;
    float* out;
    unsigned short* fbf; unsigned short* hpre;
    unsigned short* wt1; unsigned short* wt2;
    float* stat;            // [256] stats1+stats2
    unsigned int* ctr;      // [2] work-steal counters
    int N; int total8; int prepUnits;
};

// ---------------------------------------------------------------------------
// phase 0: zero stat/ctr | W1->Wt1 | W2->Wt2 (B-frag order) | feats->bf16
// ---------------------------------------------------------------------------
__device__ __forceinline__ void phase_prep(const MegaParams& p)
{
    for (int b = blockIdx.x; b < p.prepUnits; b += gridDim.x) {
        if (b == 0) {
            p.stat[threadIdx.x] = 0.f;
            if (threadIdx.x < 2) p.ctr[threadIdx.x] = 0u;
            continue;
        }
        if (b <= 108) {
            const float* W = (b <= 54) ? p.W1 : p.W2;
            unsigned short* Wt = (b <= 54) ? p.wt1 : p.wt2;
            const int t = (b <= 54 ? b - 1 : b - 55) * 256 + threadIdx.x;
            const int l  = t & 63;
            const int ct = (t >> 6) & 3;
            const int s  = (t >> 8) & 1;
            const int k  = t >> 9;
            const int d     = ct * 16 + (l & 15);
            const int cbase = s * 32 + (l >> 4) * 8;
            u16x8 o;
#pragma unroll
            for (int j = 0; j < 8; ++j)
                o[j] = f2bf(W[(size_t)k * 4096 + (size_t)(cbase + j) * 64 + d]);
            reinterpret_cast<u16x8*>(Wt)[t] = o;
            continue;
        }
        const int idx = (b - 109) * 256 + threadIdx.x;
        if (idx >= p.total8) continue;
        const float4* xp = reinterpret_cast<const float4*>(p.feats) + (size_t)idx * 2;
        const float4 a = xp[0], c = xp[1];
        u16x8 o;
        o[0] = f2bf(a.x); o[1] = f2bf(a.y); o[2] = f2bf(a.z); o[3] = f2bf(a.w);
        o[4] = f2bf(c.x); o[5] = f2bf(c.y); o[6] = f2bf(c.z); o[7] = f2bf(c.w);
        reinterpret_cast<u16x8*>(p.fbf)[idx] = o;
    }
}

// apply per-channel affine+relu to an A fragment (channels sf*32+quad*8+j)
__device__ __forceinline__ bf16x8 bn_frag(bf16x8 a, const float* sc, const float* sh) {
    u16x8 u = (u16x8)a;
    u16x8 o;
#pragma unroll
    for (int j = 0; j < 8; ++j) {
        float f = __uint_as_float((unsigned)u[j] << 16);
        f = fmaxf(fmaf(f, sc[j], sh[j]), 0.f);
        o[j] = f2bf(f);
    }
    return (bf16x8)o;
}

// ---------------------------------------------------------------------------
// One conv pass (R5-verified barrier-free wave loop), work-stolen 32-voxel
// tiles. BN=true folds relu(bn1(x)) into the gathered A-fragments.
// ---------------------------------------------------------------------------
template <bool BN, typename OUT_T>
__device__ __forceinline__ void conv_phase(
    const MegaParams& p, const unsigned short* fin, const unsigned short* Wt,
    const float* bias, OUT_T* outp, float* statp, unsigned int* ctr, int* sw,
    const float* g, const float* be, const float* statIn)
{
    const int lane = threadIdx.x & 63;
    const int m    = lane & 15;
    const int quad = lane >> 4;
    const int N    = p.N;
    const float invN = 1.0f / (float)N;
    const int ntiles = (N + 31) >> 5;

    float scv[2][8], shv[2][8];
    if (BN) {
#pragma unroll
        for (int sf = 0; sf < 2; ++sf)
#pragma unroll
            for (int j = 0; j < 8; ++j) {
                const int c = sf * 32 + quad * 8 + j;
                const float mu  = statIn[c] * invN;
                const float var = statIn[64 + c] * invN - mu * mu;
                const float rs  = rsqrtf(var + EPSV);
                scv[sf][j] = g[c] * rs;
                shv[sf][j] = be[c] - mu * scv[sf][j];
            }
    }
    float bv4[4];
#pragma unroll
    for (int ct = 0; ct < 4; ++ct) bv4[ct] = bias[ct * 16 + m];

    float sacc[4] = {0.f, 0.f, 0.f, 0.f};
    float qacc[4] = {0.f, 0.f, 0.f, 0.f};
    const char* finB = (const char*)fin;

    for (;;) {
        int tile = 0;
        if (lane == 0) tile = (int)atomicAdd(ctr, 1u);
        tile = __shfl(tile, 0, 64);
        if (tile >= ntiles) break;
        const int n0 = tile * 32;

        {   // stage this tile's indices, pre-scaled to byte offsets
            int rem = N - n0;
            rem = rem < 0 ? 0 : (rem > 32 ? 32 : rem);
            const int maxi = rem * KOFF;
            const int* nb  = p.nbr + (size_t)n0 * KOFF;
            for (int pp = lane; pp < 32 * KOFF; pp += 64)
                sw[pp] = ((pp < maxi) ? nb[pp] : 0) * (NCH * 2);
        }

        f32x4 acc[2][4];
#pragma unroll
        for (int mt = 0; mt < 2; ++mt)
#pragma unroll
            for (int ct = 0; ct < 4; ++ct) acc[mt][ct] = (f32x4){0.f, 0.f, 0.f, 0.f};

        bf16x8 A[2][2][2];   // [buf][m-tile][s]
        bf16x8 B[2][2][4];   // [buf][s][ct]

#define LOADK(kk, pbuf)                                                       \
    {                                                                         \
        const char* fp0 = finB + sw[(0 * 16 + m) * KOFF + (kk)] + quad * 16;  \
        const char* fp1 = finB + sw[(1 * 16 + m) * KOFF + (kk)] + quad * 16;  \
        A[pbuf][0][0] = *reinterpret_cast<const bf16x8*>(fp0);                \
        A[pbuf][0][1] = *reinterpret_cast<const bf16x8*>(fp0 + 64);           \
        A[pbuf][1][0] = *reinterpret_cast<const bf16x8*>(fp1);                \
        A[pbuf][1][1] = *reinterpret_cast<const bf16x8*>(fp1 + 64);           \
        const unsigned short* wp = Wt + (size_t)(kk) * 4096 + lane * 8;       \
        _Pragma("unroll")                                                     \
        for (int sf = 0; sf < 2; ++sf)                                        \
            _Pragma("unroll")                                                 \
            for (int ct = 0; ct < 4; ++ct)                                    \
                B[pbuf][sf][ct] =                                             \
                    *reinterpret_cast<const bf16x8*>(wp + (sf * 4 + ct) * 512);\
    }

#define DOMFMA(pbuf)                                                          \
    {                                                                         \
        _Pragma("unroll")                                                     \
        for (int mt = 0; mt < 2; ++mt)                                        \
            _Pragma("unroll")                                                 \
            for (int sf = 0; sf < 2; ++sf) {                                  \
                bf16x8 af = A[pbuf][mt][sf];                                  \
                if (BN) af = bn_frag(af, scv[sf], shv[sf]);                   \
                _Pragma("unroll")                                             \
                for (int ct = 0; ct < 4; ++ct)                                \
                    acc[mt][ct] = __builtin_amdgcn_mfma_f32_16x16x32_bf16(    \
                        af, B[pbuf][sf][ct], acc[mt][ct], 0, 0, 0);           \
            }                                                                 \
    }

        LOADK(0, 0);
#pragma unroll 1
        for (int k = 0; k + 2 < KOFF; k += 2) {
            LOADK(k + 1, 1);
            DOMFMA(0);
            LOADK(k + 2, 0);
            DOMFMA(1);
        }
        DOMFMA(0);   // k = 26
#undef LOADK
#undef DOMFMA

        // epilogue: D layout col=lane&15, row=quad*4+reg
#pragma unroll
        for (int ct = 0; ct < 4; ++ct) {
            const int ch = ct * 16 + m;
#pragma unroll
            for (int mt = 0; mt < 2; ++mt) {
#pragma unroll
                for (int r = 0; r < 4; ++r) {
                    const int vox = n0 + mt * 16 + quad * 4 + r;
                    if (vox < N) {
                        const float v = acc[mt][ct][r] + bv4[ct];
                        if constexpr (__is_same(OUT_T, unsigned short))
                            outp[(size_t)vox * NCH + ch] = f2bf(v);
                        else
                            outp[(size_t)vox * NCH + ch] = v;
                        sacc[ct] += v;
                        qacc[ct] += v * v;
                    }
                }
            }
        }
    }

    // per-wave stats flush: one atomic set per wave
#pragma unroll
    for (int ct = 0; ct < 4; ++ct) {
        float s = sacc[ct], q = qacc[ct];
        s += __shfl_xor(s, 16, 64);
        s += __shfl_xor(s, 32, 64);
        q += __shfl_xor(q, 16, 64);
        q += __shfl_xor(q, 32, 64);
        if (quad == 0) {
            atomicAdd(&statp[ct * 16 + m], s);
            atomicAdd(&statp[64 + ct * 16 + m], q);
        }
    }
}

// ---------------------------------------------------------------------------
// phase 3: bn2 + residual + relu, in-place on out (grid-stride)
// ---------------------------------------------------------------------------
__device__ __forceinline__ void phase_post(const MegaParams& p)
{
    const int total4 = p.N * (NCH / 4);
    const float invN = 1.0f / (float)p.N;
    const float* st2 = p.stat + 128;
    for (int idx = blockIdx.x * 256 + threadIdx.x; idx < total4;
         idx += gridDim.x * 256) {
        float4 v = reinterpret_cast<float4*>(p.out)[idx];
        const float4 f = reinterpret_cast<const float4*>(p.feats)[idx];
        const int c0 = (idx & 15) * 4;
#pragma unroll
        for (int i = 0; i < 4; ++i) {
            const int c = c0 + i;
            const float mu  = st2[c] * invN;
            const float var = st2[64 + c] * invN - mu * mu;
            const float rs  = rsqrtf(var + EPSV);
            const float sc  = p.g2[c] * rs;
            const float sh  = p.be2[c] - mu * sc;
            float* vv = reinterpret_cast<float*>(&v) + i;
            const float ff = reinterpret_cast<const float*>(&f)[i];
            *vv = fmaxf(fmaf(*vv, sc, sh) + ff, 0.f);
        }
        reinterpret_cast<float4*>(p.out)[idx] = v;
    }
}

// ---------------------------------------------------------------------------
// Cooperative mega-kernel: prep | conv1 | conv2(+fused bn1+relu) | bn2+res
// ---------------------------------------------------------------------------
__global__ __launch_bounds__(256, 2)
void mega_kernel(MegaParams p)
{
    __shared__ int s_idx[4 * 32 * KOFF];
    cg::grid_group grid = cg::this_grid();
    int* sw = s_idx + (threadIdx.x >> 6) * (32 * KOFF);

    phase_prep(p);
    __threadfence();
    grid.sync();

    conv_phase<false, unsigned short>(p, p.fbf, p.wt1, p.b1, p.hpre, p.stat,
                                      p.ctr + 0, sw, nullptr, nullptr, nullptr);
    __threadfence();
    grid.sync();

    conv_phase<true, float>(p, p.hpre, p.wt2, p.b2, p.out, p.stat + 128,
                            p.ctr + 1, sw, p.g1, p.be1, p.stat);
    __threadfence();
    grid.sync();

    phase_post(p);
}

// ---- fallback: identical phases as 4 plain dispatches ----
__global__ __launch_bounds__(256) void k_prep(MegaParams p) { phase_prep(p); }
__global__ __launch_bounds__(256, 2) void k_conv1(MegaParams p) {
    __shared__ int s_idx[4 * 32 * KOFF];
    int* sw = s_idx + (threadIdx.x >> 6) * (32 * KOFF);
    conv_phase<false, unsigned short>(p, p.fbf, p.wt1, p.b1, p.hpre, p.stat,
                                      p.ctr + 0, sw, nullptr, nullptr, nullptr);
}
__global__ __launch_bounds__(256, 2) void k_conv2(MegaParams p) {
    __shared__ int s_idx[4 * 32 * KOFF];
    int* sw = s_idx + (threadIdx.x >> 6) * (32 * KOFF);
    conv_phase<true, float>(p, p.hpre, p.wt2, p.b2, p.out, p.stat + 128,
                            p.ctr + 1, sw, p.g1, p.be1, p.stat);
}
__global__ __launch_bounds__(256) void k_post(MegaParams p) { phase_post(p); }

extern "C" void kernel_launch(void* const* d_in, const int* in_sizes, int n_in,
                              void* d_out, int out_size, void* d_ws, size_t ws_size,
                              hipStream_t stream)
{
    const int N  = in_sizes[0] / NCH;          // 100000
    const int NC = N * NCH;                    // 6,400,000

    unsigned short* fbf  = (unsigned short*)d_ws;              // [N*C] bf16
    unsigned short* hpre = fbf + NC;                           // [N*C] bf16
    unsigned short* wt1  = hpre + NC;                          // 110592 bf16
    unsigned short* wt2  = wt1 + KOFF * 4096;                  // 110592 bf16
    float*          stat = (float*)(wt2 + KOFF * 4096);        // 256 fp32
    unsigned int*   ctr  = (unsigned int*)(stat + 256);        // 2 u32

    MegaParams P;
    P.feats = (const float*)d_in[0];
    P.nbr   = (const int*)d_in[1];
    P.W1    = (const float*)d_in[2];
    P.b1    = (const float*)d_in[3];
    P.g1    = (const float*)d_in[4];
    P.be1   = (const float*)d_in[5];
    P.W2    = (const float*)d_in[6];
    P.b2    = (const float*)d_in[7];
    P.g2    = (const float*)d_in[8];
    P.be2   = (const float*)d_in[9];
    P.out   = (float*)d_out;
    P.fbf   = fbf;  P.hpre = hpre;
    P.wt1   = wt1;  P.wt2  = wt2;
    P.stat  = stat; P.ctr  = ctr;
    P.N     = N;
    P.total8 = NC / 8;                         // 800000
    P.prepUnits = 1 + 108 + (P.total8 + 255) / 256;   // 3234

    // grid = measured residency (blocks/CU) x 256 CUs, never over-subscribed
    bool done = false;
    int bpc = 0;
    if (hipOccupancyMaxActiveBlocksPerMultiprocessor(
            &bpc, (const void*)mega_kernel, 256, 0) == hipSuccess && bpc > 0) {
        int grid = bpc * 256;
        if (grid > 2048) grid = 2048;
        void* args[] = { &P };
        if (hipLaunchCooperativeKernel((const void*)mega_kernel, dim3(grid),
                                       dim3(256), args, 0, stream) == hipSuccess)
            done = true;
    }
    if (!done) {   // plain-dispatch fallback, same device code
        k_prep <<<P.prepUnits, 256, 0, stream>>>(P);
        k_conv1<<<768, 256, 0, stream>>>(P);
        k_conv2<<<768, 256, 0, stream>>>(P);
        k_post <<<(N * (NCH / 4) + 255) / 256, 256, 0, stream>>>(P);
    }
}